// Round 6
// baseline (477.996 us; speedup 1.0000x reference)
//
#include <hip/hip_runtime.h>

// ============================================================================
// AdapterAttention on gfx950.
// R8: GEMMs converged on the verified m201 geometry: BM=BN=256, BK=32, 512
//     threads = 8 waves (2Mx4N, wave-tile 128x64), ONE barrier domain/CU,
//     ring-3 LDS (96KB, 1 block/CU). Staging halved vs R7 (A+B staged once
//     per 256-row panel: 4 loads/thread/K32), gate once/K32 at vmcnt(4).
//     Phase split (2 phases x 16 MFMA), ring ordering, swizzle carried from
//     verified R7 core. R7 lesson: phase shape alone was null at 2x4-wave
//     blocks — the deltas to m201 were domain structure + staging volume.
//     Also: 6 castbf launches merged into 1. flash unchanged (R6).
// ============================================================================

typedef __attribute__((ext_vector_type(8))) short bf16x8;
typedef __attribute__((ext_vector_type(4))) float f32x4;

#define AS1(p) ((__attribute__((address_space(1))) void*)(p))
#define AS3(p) ((__attribute__((address_space(3))) void*)(p))
#define STG(g, l) __builtin_amdgcn_global_load_lds(AS1(g), AS3(l), 16, 0, 0)

__device__ __forceinline__ unsigned short f2bf(float f) {
  unsigned int u = __float_as_uint(f);
  u += 0x7fffu + ((u >> 16) & 1u);   // RNE; inputs are finite
  return (unsigned short)(u >> 16);
}
__device__ __forceinline__ float bf2f(unsigned short u) {
  return __uint_as_float(((unsigned int)u) << 16);
}

constexpr int B_ = 2, S_ = 2048, DM = 2048, H_ = 16, HD = 128;
constexpr int M_ = B_ * S_;  // 4096 rows

// ---------------- fp32 -> bf16 cast, all 6 tensors in one launch ------------
__global__ __launch_bounds__(256) void castall(const float* __restrict__ x,
                                               const float* __restrict__ ctx,
                                               const float* __restrict__ Wq,
                                               const float* __restrict__ Wk,
                                               const float* __restrict__ Wv,
                                               const float* __restrict__ Wo,
                                               unsigned short* __restrict__ xb,
                                               unsigned short* __restrict__ cb,
                                               unsigned short* __restrict__ Wqb,
                                               unsigned short* __restrict__ Wkb,
                                               unsigned short* __restrict__ Wvb,
                                               unsigned short* __restrict__ Wob) {
  constexpr int A4 = M_ * DM / 4;   // float4 per activation
  constexpr int W4 = DM * DM / 4;   // float4 per weight
  int i = blockIdx.x * 256 + threadIdx.x;
  const float* src; unsigned short* dst; int off;
  if (i < A4)                { src = x;   dst = xb;  off = i; }
  else if (i < 2 * A4)       { src = ctx; dst = cb;  off = i - A4; }
  else if (i < 2 * A4 + W4)  { src = Wq;  dst = Wqb; off = i - 2 * A4; }
  else if (i < 2 * A4 + 2 * W4) { src = Wk; dst = Wkb; off = i - 2 * A4 - W4; }
  else if (i < 2 * A4 + 3 * W4) { src = Wv; dst = Wvb; off = i - 2 * A4 - 2 * W4; }
  else                       { src = Wo;  dst = Wob; off = i - 2 * A4 - 3 * W4; }
  float4 v = ((const float4*)src)[off];
  ushort4 u;
  u.x = f2bf(v.x); u.y = f2bf(v.y); u.z = f2bf(v.z); u.w = f2bf(v.w);
  ((ushort4*)dst)[off] = u;
}

// ---------------- single-domain 256x256 GEMM core: C = A * W^T --------------
// BM=BN=256, BK=32. 512 threads = 8 waves (2M x 4N); wave-tile 128x64 =
// 8x4 frags = 32 MFMA per K-step per wave. LDS ring: 3 slots x 32 KB
// (A 16 KB + B 16 KB) = 96 KB -> 1 block/CU, one barrier domain.
// LDS packing per matrix: line L (128 B, 8 chunks of 16 B) holds rows
// {L, L+128}, k-chunks 0..3 each; phys chunk = j ^ (L&7), j = (rowhalf<<2)|kc.
// Staged via pre-swizzled per-lane global sources, linear LDS dest.
// Per K-step: phase A {8 ds_read | stage A(t+2) 2 loads | barrier | 16 MFMA |
// barrier}, phase B {4 ds_read | stage B(t+2) 2 loads | vmcnt(4) gate |
// barrier | 16 MFMA | barrier}. Stage targets slot (t+2)%3 (never the slot
// being read; last reader sealed 2 barriers earlier). Drain only at tail.
template <int BF16OUT>
__device__ __forceinline__ void gemm_core(const unsigned short* __restrict__ A,
                                          const unsigned short* __restrict__ Bw,
                                          void* __restrict__ Cv,
                                          unsigned short* lds) {
  const int tid = threadIdx.x, wave = tid >> 6, lane = tid & 63;
  const int quad = lane >> 4, l16 = lane & 15;
  const int m0 = blockIdx.x * 256, n0 = blockIdx.y * 256;
  const int wm = (wave >> 2) * 128, wn = (wave & 3) * 64;
  constexpr int NT = DM / 32;     // 64 K-steps
  constexpr int SLOT = 16384;     // shorts per ring slot (32 KB)

  f32x4 acc[8][4];
#pragma unroll
  for (int f = 0; f < 8; f++)
#pragma unroll
    for (int g = 0; g < 4; g++) acc[f][g] = (f32x4){0.f, 0.f, 0.f, 0.f};

  // -- staging sources (per-lane, pre-swizzled). Chunk c in [0,1024):
  //    L=c>>3, ph=c&7, j=ph^(L&7); element = row (L + (j>>2)*128), k-chunk j&3.
  const unsigned short* srcA[2];
  const unsigned short* srcB[2];
  int wst[2];
#pragma unroll
  for (int i = 0; i < 2; i++) {
    int c = tid + i * 512, L = c >> 3, ph = c & 7, j = ph ^ (L & 7);
    srcA[i] = A + (size_t)(m0 + L + ((j >> 2) << 7)) * DM + (j & 3) * 8;
    srcB[i] = Bw + (size_t)(n0 + L + ((j >> 2) << 7)) * DM + (j & 3) * 8;
    wst[i] = (i * 512 + wave * 64) * 8;  // wave-uniform LDS dest (+lane*16B HW)
  }

#define STAGE_A(T, S)                                                          \
  { const int ko = (T) << 5;                                                   \
    STG(srcA[0] + ko, lds + (S) * SLOT + wst[0]);                              \
    STG(srcA[1] + ko, lds + (S) * SLOT + wst[1]); }
#define STAGE_B(T, S)                                                          \
  { const int ko = (T) << 5;                                                   \
    STG(srcB[0] + ko, lds + (S) * SLOT + 8192 + wst[0]);                       \
    STG(srcB[1] + ko, lds + (S) * SLOT + 8192 + wst[1]); }

  // -- read-side bases (shorts). A frag f: row r = wm+f*16+l16, line r&127 =
  //    f*16+l16, phys = ((wave>>2)<<2 | quad) ^ (l16&7). B frag g likewise.
  const int x8 = l16 & 7;
  const int abase = l16 * 64 + ((((wave >> 2) << 2) | quad) ^ x8) * 8;
  const int bbase = 8192 + (wn & 64) * 64 + l16 * 64 +
                    ((((wave >> 1) & 1) << 2 | quad) ^ x8) * 8;

  // -- prologue: stage tiles 0,1; gate tile 0 (tile 1's 4 stay in flight) --
  STAGE_A(0, 0) STAGE_B(0, 0)
  STAGE_A(1, 1) STAGE_B(1, 1)
  asm volatile("s_waitcnt vmcnt(4)" ::: "memory");
  __builtin_amdgcn_s_barrier();

  int st = 0, s2 = 2;
  for (int t = 0; t < NT; ++t) {
    const unsigned short* ls = lds + st * SLOT;

    // ---- phase A: A frags 0..3 + all B frags; stage A-half of tile t+2 ----
    bf16x8 af0[4], bfv[4];
#pragma unroll
    for (int f = 0; f < 4; f++) af0[f] = *(const bf16x8*)(ls + f * 1024 + abase);
#pragma unroll
    for (int g = 0; g < 4; g++) bfv[g] = *(const bf16x8*)(ls + g * 1024 + bbase);
    if (t + 2 < NT) STAGE_A(t + 2, s2)
    __builtin_amdgcn_s_barrier();
    __builtin_amdgcn_s_setprio(1);
#pragma unroll
    for (int f = 0; f < 4; f++)
#pragma unroll
      for (int g = 0; g < 4; g++)
        acc[f][g] = __builtin_amdgcn_mfma_f32_16x16x32_bf16(af0[f], bfv[g], acc[f][g], 0, 0, 0);
    __builtin_amdgcn_s_setprio(0);
    __builtin_amdgcn_s_barrier();

    // ---- phase B: A frags 4..7 (B reused); stage B-half; gate once/K-step --
    bf16x8 af1[4];
#pragma unroll
    for (int f = 0; f < 4; f++) af1[f] = *(const bf16x8*)(ls + (f + 4) * 1024 + abase);
    if (t + 2 < NT) STAGE_B(t + 2, s2)
    // gate: tile t+1 fully landed; tile t+2's 4 loads stay in flight
    if (t < NT - 2)       asm volatile("s_waitcnt vmcnt(4)" ::: "memory");
    else if (t == NT - 2) asm volatile("s_waitcnt vmcnt(0)" ::: "memory");
    __builtin_amdgcn_s_barrier();
    __builtin_amdgcn_s_setprio(1);
#pragma unroll
    for (int f = 0; f < 4; f++)
#pragma unroll
      for (int g = 0; g < 4; g++)
        acc[f + 4][g] = __builtin_amdgcn_mfma_f32_16x16x32_bf16(af1[f], bfv[g], acc[f + 4][g], 0, 0, 0);
    __builtin_amdgcn_s_setprio(0);
    if (t < NT - 1) __builtin_amdgcn_s_barrier();

    st++; if (st == 3) st = 0;
    s2++; if (s2 == 3) s2 = 0;
  }
#undef STAGE_A
#undef STAGE_B

  // ---- epilogue: C write ----
#pragma unroll
  for (int f = 0; f < 8; f++)
#pragma unroll
    for (int g = 0; g < 4; g++) {
      const size_t row = (size_t)(m0 + wm + f * 16 + quad * 4);
      const int col = n0 + wn + g * 16 + l16;
      if (BF16OUT) {
        unsigned short* cp = (unsigned short*)Cv + row * DM + col;
#pragma unroll
        for (int r = 0; r < 4; r++) cp[(size_t)r * DM] = f2bf(acc[f][g][r]);
      } else {
        float* cp = (float*)Cv + row * DM + col;
#pragma unroll
        for (int r = 0; r < 4; r++) cp[(size_t)r * DM] = acc[f][g][r];
      }
    }
}

// ---------------- batched QKV GEMM: P[z] = A[z] * W[z]^T, bf16 out ----------
__global__ __launch_bounds__(512, 2) void gemm_qkv(const unsigned short* __restrict__ xb,
                                                   const unsigned short* __restrict__ cb,
                                                   const unsigned short* __restrict__ Wq,
                                                   const unsigned short* __restrict__ Wk,
                                                   const unsigned short* __restrict__ Wv,
                                                   unsigned short* __restrict__ Pq,
                                                   unsigned short* __restrict__ Pk,
                                                   unsigned short* __restrict__ Pv) {
  __shared__ __align__(16) unsigned short lds[3 * 16384];  // 96 KiB
  const int z = blockIdx.z;
  const unsigned short* A  = (z == 0) ? xb : cb;
  const unsigned short* Bw = (z == 0) ? Wq : (z == 1) ? Wk : Wv;
  unsigned short* C        = (z == 0) ? Pq : (z == 1) ? Pk : Pv;
  gemm_core<1>(A, Bw, C, lds);
}

// ---------------- bf16 GEMM: C = A * W^T (fp32 out), for out-proj -----------
__global__ __launch_bounds__(512, 2) void gemm_bt(const unsigned short* __restrict__ A,
                                                  const unsigned short* __restrict__ Bw,
                                                  float* __restrict__ C) {
  __shared__ __align__(16) unsigned short lds[3 * 16384];  // 96 KiB
  gemm_core<0>(A, Bw, C, lds);
}

// ---------------- fused RMSNorm + RoPE, bf16 (B,S,H,hd) -> (B,H,S,hd) bf16 --
__global__ __launch_bounds__(256) void normrope(const unsigned short* __restrict__ X,
                                                const float* __restrict__ Cs,
                                                const float* __restrict__ Sn,
                                                const float* __restrict__ W,
                                                unsigned short* __restrict__ Out,
                                                float scale) {
  int gw = (blockIdx.x * 256 + threadIdx.x) >> 6;  // (b*S+s)*H + h
  int lane = threadIdx.x & 63;
  int h = gw & 15, bs = gw >> 4;          // bs = b*S + s
  int s = bs & (S_ - 1), b = bs >> 11;
  const unsigned short* xr = X + (size_t)gw * HD;
  float x0 = bf2f(xr[lane]), x1 = bf2f(xr[lane + 64]);
  float ss = x0 * x0 + x1 * x1;
#pragma unroll
  for (int off = 32; off > 0; off >>= 1) ss += __shfl_xor(ss, off);
  float rr = rsqrtf(ss * (1.0f / 128.0f) + 1e-6f);
  float n0 = x0 * rr * W[lane], n1 = x1 * rr * W[lane + 64];
  const float* cp = Cs + (size_t)bs * HD;
  const float* sp = Sn + (size_t)bs * HD;
  float o0 = (n0 * cp[lane] - n1 * sp[lane]) * scale;
  float o1 = (n1 * cp[lane + 64] + n0 * sp[lane + 64]) * scale;
  unsigned short* orow = Out + (((size_t)(b * H_ + h)) * S_ + s) * HD;
  orow[lane] = f2bf(o0);
  orow[lane + 64] = f2bf(o1);
}

// ---------------- V: bf16 (B,S,H,hd) -> (B*H, hd, Sk) bf16 (transposed) -----
__global__ __launch_bounds__(256) void vtrans(const unsigned short* __restrict__ Vf,
                                              unsigned short* __restrict__ Vt) {
  __shared__ unsigned short tile[128 * 72];  // [d][s], stride 72
  const int tid = threadIdx.x;
  const int sc = blockIdx.x & 31;
  const int bh = blockIdx.x >> 5;
  const int b = bh >> 4, h = bh & 15;
  const int s0 = sc * 64;
#pragma unroll
  for (int it = 0; it < 4; ++it) {
    int ci = it * 256 + tid;                  // 1024 chunks: 64 s x 16 dc
    int s = ci >> 4, dc = ci & 15;
    bf16x8 v = *(const bf16x8*)(Vf + ((size_t)(b * S_ + s0 + s)) * DM + h * HD + dc * 8);
    unsigned short* tp = tile + (dc * 8) * 72 + s;
#pragma unroll
    for (int e = 0; e < 8; e++) tp[e * 72] = (unsigned short)v[e];
  }
  __syncthreads();
#pragma unroll
  for (int it = 0; it < 4; ++it) {
    int cj = it * 256 + tid;                  // 1024 16B chunks: 128 d x 8 sc
    int d = cj >> 3, scx = cj & 7;
    bf16x8 vv = *(const bf16x8*)(tile + d * 72 + scx * 8);
    *(bf16x8*)(Vt + ((size_t)bh * HD + d) * S_ + s0 + scx * 8) = vv;
  }
}

// ---------------- flash attention v4 (R6, unchanged) ----------------
// 256 threads (4 waves), 128 q-rows/block (32/wave), 64-key chunks.
// K/V double-buffered; stage t+1 during compute of t; counted vmcnt(8);
// raw s_barriers; drain only at final iter. Grid 512 = 2 blocks/CU.
__global__ __launch_bounds__(256, 2) void flash(const unsigned short* __restrict__ Q,
                                                const unsigned short* __restrict__ Kt,
                                                const unsigned short* __restrict__ Vt,
                                                unsigned short* __restrict__ Y) {
  __shared__ unsigned short lK[2 * 64 * HD];  // [buf][key][dim], chunk-swizzled
  __shared__ unsigned short lV[2 * HD * 64];  // [buf][dim][key], chunk-swizzled
  __shared__ unsigned short lP[4 * 1024];     // per-wave P scratch (reused per half)
  const int tid = threadIdx.x, wave = tid >> 6, lane = tid & 63;
  const int quad = lane >> 4, l16 = lane & 15;
  const int qb = blockIdx.x & 15;   // Sq/128
  const int bh = blockIdx.x >> 4;
  const int b = bh >> 4, h = bh & 15;
  const int q0 = qb * 128 + wave * 32;

  bf16x8 aq[2][4];
#pragma unroll
  for (int u = 0; u < 2; u++) {
    const unsigned short* qrow = Q + ((size_t)bh * S_ + q0 + u * 16 + l16) * HD;
#pragma unroll
    for (int t = 0; t < 4; t++) aq[u][t] = *(const bf16x8*)(qrow + t * 32 + quad * 8);
  }
  f32x4 o[2][8];
#pragma unroll
  for (int u = 0; u < 2; u++)
#pragma unroll
    for (int t = 0; t < 8; t++) o[u][t] = (f32x4){0.f, 0.f, 0.f, 0.f};
  float lsum[2][4] = {{0.f, 0.f, 0.f, 0.f}, {0.f, 0.f, 0.f, 0.f}};

  const unsigned short* kbase = Kt + (size_t)bh * S_ * HD;
  const unsigned short* vbase = Vt + (size_t)bh * HD * S_;
  unsigned short* lPw = lP + wave * 1024;
  const int mrow = quad * 4;
  const int xsl = (l16 >> 1) & 3;    // P-read swizzle (4 chunks per 32-key row)
  const int xsl7 = (l16 >> 1) & 7;   // V-read swizzle (8 chunks per 64-key row)

#define STAGEKV(K0, BUF)                                                       \
  {                                                                            \
    const unsigned short* kb_ = kbase + (size_t)(K0) * HD;                     \
    const unsigned short* vb_ = vbase + (K0);                                  \
    _Pragma("unroll")                                                          \
    for (int call = 0; call < 4; ++call) {                                     \
      int c = call * 256 + tid;               /* chunk id [0,1024) */          \
      int key = c >> 4, sk = c & 15;          /* K: 64 keys x 16 dim-chunks */ \
      int dck = sk ^ (key & 15);                                               \
      STG(kb_ + (size_t)key * HD + dck * 8,                                    \
          lK + (BUF) * 8192 + (call * 256 + wave * 64) * 8);                   \
      int dv = c >> 3, sv = c & 7;            /* V: 128 dims x 8 key-chunks */ \
      int kc = sv ^ ((dv >> 1) & 7);                                           \
      STG(vb_ + (size_t)dv * S_ + kc * 8,                                      \
          lV + (BUF) * 8192 + (call * 256 + wave * 64) * 8);                   \
    }                                                                          \
  }

  STAGEKV(0, 0)

  for (int it = 0; it < S_ / 64; ++it) {
    if (it + 1 < S_ / 64) {
      STAGEKV((it + 1) * 64, (it + 1) & 1)
      asm volatile("s_waitcnt vmcnt(8)" ::: "memory");
    } else {
      asm volatile("s_waitcnt vmcnt(0)" ::: "memory");
    }
    __builtin_amdgcn_s_barrier();   // publish all waves' stages of tile `it`

    const unsigned short* lKc = lK + (it & 1) * 8192;
    const unsigned short* lVc = lV + (it & 1) * 8192;

#pragma unroll
    for (int h2 = 0; h2 < 2; ++h2) {          // two 32-key halves
      f32x4 s0[2] = {(f32x4){0.f, 0.f, 0.f, 0.f}, (f32x4){0.f, 0.f, 0.f, 0.f}};
      f32x4 s1[2] = {(f32x4){0.f, 0.f, 0.f, 0.f}, (f32x4){0.f, 0.f, 0.f, 0.f}};
      {
        const unsigned short* krow0 = lKc + (h2 * 32 + l16) * HD;
        const unsigned short* krow1 = krow0 + 16 * HD;
        __builtin_amdgcn_s_setprio(1);
#pragma unroll
        for (int t = 0; t < 4; t++) {
          int dcq = t * 4 + quad;
          bf16x8 kf0 = *(const bf16x8*)(krow0 + (dcq ^ l16) * 8);
          bf16x8 kf1 = *(const bf16x8*)(krow1 + (dcq ^ l16) * 8);
#pragma unroll
          for (int u = 0; u < 2; u++) {
            s0[u] = __builtin_amdgcn_mfma_f32_16x16x32_bf16(aq[u][t], kf0, s0[u], 0, 0, 0);
            s1[u] = __builtin_amdgcn_mfma_f32_16x16x32_bf16(aq[u][t], kf1, s1[u], 0, 0, 0);
          }
        }
        __builtin_amdgcn_s_setprio(0);
      }
#pragma unroll
      for (int u = 0; u < 2; u++) {
        unsigned short* lPu = lPw + u * 512;
#pragma unroll
        for (int r = 0; r < 4; r++) {
          int m = mrow + r;
          int sx = (m >> 1) & 3;
          float p0 = __expf(s0[u][r]);
          float p1 = __expf(s1[u][r]);
          lsum[u][r] += p0 + p1;
          int kc0 = l16 >> 3;
          lPu[m * 32 + ((kc0 ^ sx)) * 8 + (l16 & 7)] = f2bf(p0);
          lPu[m * 32 + (((kc0 + 2) ^ sx)) * 8 + (l16 & 7)] = f2bf(p1);
        }
      }
      bf16x8 pf[2];
#pragma unroll
      for (int u = 0; u < 2; u++)
        pf[u] = *(const bf16x8*)(lPw + u * 512 + l16 * 32 + (quad ^ xsl) * 8);
      __builtin_amdgcn_s_setprio(1);
#pragma unroll
      for (int t = 0; t < 8; t++) {
        bf16x8 vf = *(const bf16x8*)(lVc + (t * 16 + l16) * 64 + ((h2 * 4 + quad) ^ xsl7) * 8);
#pragma unroll
        for (int u = 0; u < 2; u++)
          o[u][t] = __builtin_amdgcn_mfma_f32_16x16x32_bf16(pf[u], vf, o[u][t], 0, 0, 0);
      }
      __builtin_amdgcn_s_setprio(0);
    }

    __builtin_amdgcn_s_barrier();   // reads of buf (it&1) done before overwrite
  }
#undef STAGEKV

#pragma unroll
  for (int off = 1; off < 16; off <<= 1) {
#pragma unroll
    for (int u = 0; u < 2; u++)
#pragma unroll
      for (int r = 0; r < 4; r++) lsum[u][r] += __shfl_xor(lsum[u][r], off);
  }
  float inv[2][4];
#pragma unroll
  for (int u = 0; u < 2; u++)
#pragma unroll
    for (int r = 0; r < 4; r++) inv[u][r] = 1.0f / lsum[u][r];
#pragma unroll
  for (int u = 0; u < 2; u++)
#pragma unroll
    for (int t = 0; t < 8; t++)
#pragma unroll
      for (int r = 0; r < 4; r++) {
        size_t idx = ((size_t)b * S_ + q0 + u * 16 + mrow + r) * DM + h * HD + t * 16 + l16;
        Y[idx] = f2bf(o[u][t][r] * inv[u][r]);
      }
}

// ============================================================================
extern "C" void kernel_launch(void* const* d_in, const int* in_sizes, int n_in,
                              void* d_out, int out_size, void* d_ws, size_t ws_size,
                              hipStream_t stream) {
  const float* x    = (const float*)d_in[0];
  const float* ctx  = (const float*)d_in[1];
  const float* cosq = (const float*)d_in[2];
  const float* sinq = (const float*)d_in[3];
  const float* cosk = (const float*)d_in[4];
  const float* sink = (const float*)d_in[5];
  const float* Wq   = (const float*)d_in[6];
  const float* Wk   = (const float*)d_in[7];
  const float* Wv   = (const float*)d_in[8];
  const float* Wo   = (const float*)d_in[9];
  const float* qw   = (const float*)d_in[10];
  const float* kw   = (const float*)d_in[11];

  // ---- workspace layout with lifetime overlap (~118 MB) ----
  char* ws = (char*)d_ws;
  const size_t ACT2 = (size_t)M_ * DM * 2;   // 16.8 MB bf16 activation
  const size_t W2   = (size_t)DM * DM * 2;   // 8.4 MB bf16 weight
  unsigned short* xb  = (unsigned short*)(ws);                    // -> qn
  unsigned short* cb  = (unsigned short*)(ws + ACT2);             // -> vt
  unsigned short* Wqb = (unsigned short*)(ws + 2 * ACT2);         // \ kn
  unsigned short* Wkb = (unsigned short*)(ws + 2 * ACT2 + W2);    // /
  unsigned short* Wvb = (unsigned short*)(ws + 2 * ACT2 + 2 * W2);
  unsigned short* Wob = (unsigned short*)(ws + 2 * ACT2 + 3 * W2);
  unsigned short* Pq  = (unsigned short*)(ws + 2 * ACT2 + 4 * W2);  // -> yb
  unsigned short* Pk  = (unsigned short*)(ws + 3 * ACT2 + 4 * W2);
  unsigned short* Pv  = (unsigned short*)(ws + 4 * ACT2 + 4 * W2);
  unsigned short* qn = xb;          // after gemm_qkv consumed xb
  unsigned short* kn = Wqb;         // spans Wqb+Wkb, dead after gemm_qkv
  unsigned short* vt = cb;          // after gemm_qkv consumed cb
  unsigned short* yb = Pq;          // after normrope consumed Pq

  const float scale = 0.0883883476483184f;  // 1/sqrt(128)

  // one cast launch for all 6 tensors: (2*ACT + 4*W)/4 float4 / 256
  castall<<<(2 * M_ * DM + 4 * DM * DM) / 1024, 256, 0, stream>>>(
      x, ctx, Wq, Wk, Wv, Wo, xb, cb, Wqb, Wkb, Wvb, Wob);

  dim3 gq(M_ / 256, DM / 256, 3);   // 16 x 8 x 3 = 384 blocks (1 per CU)
  gemm_qkv<<<gq, 512, 0, stream>>>(xb, cb, Wqb, Wkb, Wvb, Pq, Pk, Pv);

  normrope<<<M_ * H_ / 4, 256, 0, stream>>>(Pq, cosq, sinq, qw, qn, scale);
  normrope<<<M_ * H_ / 4, 256, 0, stream>>>(Pk, cosk, sink, kw, kn, 1.0f);
  vtrans<<<B_ * H_ * (S_ / 64), 256, 0, stream>>>(Pv, vt);

  flash<<<B_ * H_ * (S_ / 128), 256, 0, stream>>>(qn, kn, vt, yb);

  dim3 gg(M_ / 256, DM / 256);      // 16 x 8 = 128 blocks
  gemm_bt<<<gg, 512, 0, stream>>>(yb, Wob, (float*)d_out);

  (void)in_sizes; (void)n_in; (void)out_size; (void)ws_size;
}

// Round 7
// 454.313 us; speedup vs baseline: 1.0521x; 1.0521x over previous
//
#include <hip/hip_runtime.h>

// ============================================================================
// AdapterAttention on gfx950.
// R9: recovery + fill fixes. R8 falsified the single-domain theory (126us vs
//     111us): 2 independent 4-wave blocks/CU beat one 8-wave domain — cross-
//     block overlap is what hides the read/gate/barrier phases. This round:
//     (1) GEMM core reverted to R7 verbatim (BM=128 BN=256 BK=32, ring-3,
//         phased, 2 blocks/CU; 111us measured twice), NT templated;
//     (2) gemm_bt split-K=2 -> 512 blocks = exact 2/CU fill (was 256 = 1/CU,
//         the worst measured concurrency config), partials + add kernel;
//     (3) normrope x2 + vtrans merged into one `prep` launch (concurrent);
//     (4) castall kept from R8; flash kept from R6.
// ============================================================================

typedef __attribute__((ext_vector_type(8))) short bf16x8;
typedef __attribute__((ext_vector_type(4))) float f32x4;

#define AS1(p) ((__attribute__((address_space(1))) void*)(p))
#define AS3(p) ((__attribute__((address_space(3))) void*)(p))
#define STG(g, l) __builtin_amdgcn_global_load_lds(AS1(g), AS3(l), 16, 0, 0)

__device__ __forceinline__ unsigned short f2bf(float f) {
  unsigned int u = __float_as_uint(f);
  u += 0x7fffu + ((u >> 16) & 1u);   // RNE; inputs are finite
  return (unsigned short)(u >> 16);
}
__device__ __forceinline__ float bf2f(unsigned short u) {
  return __uint_as_float(((unsigned int)u) << 16);
}

constexpr int B_ = 2, S_ = 2048, DM = 2048, H_ = 16, HD = 128;
constexpr int M_ = B_ * S_;  // 4096 rows

// ---------------- fp32 -> bf16 cast, all 6 tensors in one launch ------------
__global__ __launch_bounds__(256) void castall(const float* __restrict__ x,
                                               const float* __restrict__ ctx,
                                               const float* __restrict__ Wq,
                                               const float* __restrict__ Wk,
                                               const float* __restrict__ Wv,
                                               const float* __restrict__ Wo,
                                               unsigned short* __restrict__ xb,
                                               unsigned short* __restrict__ cb,
                                               unsigned short* __restrict__ Wqb,
                                               unsigned short* __restrict__ Wkb,
                                               unsigned short* __restrict__ Wvb,
                                               unsigned short* __restrict__ Wob) {
  constexpr int A4 = M_ * DM / 4;   // float4 per activation
  constexpr int W4 = DM * DM / 4;   // float4 per weight
  int i = blockIdx.x * 256 + threadIdx.x;
  const float* src; unsigned short* dst; int off;
  if (i < A4)                { src = x;   dst = xb;  off = i; }
  else if (i < 2 * A4)       { src = ctx; dst = cb;  off = i - A4; }
  else if (i < 2 * A4 + W4)  { src = Wq;  dst = Wqb; off = i - 2 * A4; }
  else if (i < 2 * A4 + 2 * W4) { src = Wk; dst = Wkb; off = i - 2 * A4 - W4; }
  else if (i < 2 * A4 + 3 * W4) { src = Wv; dst = Wvb; off = i - 2 * A4 - 2 * W4; }
  else                       { src = Wo;  dst = Wob; off = i - 2 * A4 - 3 * W4; }
  float4 v = ((const float4*)src)[off];
  ushort4 u;
  u.x = f2bf(v.x); u.y = f2bf(v.y); u.z = f2bf(v.z); u.w = f2bf(v.w);
  ((ushort4*)dst)[off] = u;
}

// ---------------- phased high-density GEMM core: C = A * W^T ----------------
// (R7 verbatim, NT templated.) BM=128, BN=256, BK=32. 256 threads = 4 waves
// (1M x 4N); wave-tile 128x64 = 8x4 frags = 32 MFMA/K-step/wave. LDS ring:
// 3 slots x 24 KB = 72 KB -> 2 blocks/CU (two independent barrier domains).
// Per K-step: phase A {8 ds_read | stage H0(t+2) | barrier | 16 MFMA |
// barrier}, phase B {4 ds_read | stage H1(t+2) | vmcnt(6) gate | barrier |
// 16 MFMA | barrier}. Stage targets slot (t+2)%3; drain only at tail.
template <int BF16OUT, int NT>
__device__ __forceinline__ void gemm_core(const unsigned short* __restrict__ A,
                                          const unsigned short* __restrict__ Bw,
                                          void* __restrict__ Cv,
                                          unsigned short* lds) {
  const int tid = threadIdx.x, wave = tid >> 6, lane = tid & 63;
  const int quad = lane >> 4, l16 = lane & 15;
  const int m0 = blockIdx.x * 128, n0 = blockIdx.y * 256;
  const int wn = wave * 64;
  constexpr int SLOT = 12288;     // shorts per ring slot (24 KB)

  f32x4 acc[8][4];
#pragma unroll
  for (int f = 0; f < 8; f++)
#pragma unroll
    for (int g = 0; g < 4; g++) acc[f][g] = (f32x4){0.f, 0.f, 0.f, 0.f};

  // -- staging sources (per-lane, pre-swizzled). Chunk c: L=c>>3, phys=c&7,
  //    j = phys ^ (L&7); stored element = row (L + rowhalf*{64|128}),
  //    k-chunk j&3. LDS dest is linear: offset c*8 shorts.
  const unsigned short* srcA[2];
  const unsigned short* srcB[4];
#pragma unroll
  for (int i = 0; i < 2; i++) {
    int c = tid + i * 256, L = c >> 3, ph = c & 7, j = ph ^ (L & 7);
    srcA[i] = A + (size_t)(m0 + L + ((j >> 2) << 6)) * DM + (j & 3) * 8;
  }
#pragma unroll
  for (int i = 0; i < 4; i++) {
    int c = tid + i * 256, L = c >> 3, ph = c & 7, j = ph ^ (L & 7);
    srcB[i] = Bw + (size_t)(n0 + L + ((j >> 2) << 7)) * DM + (j & 3) * 8;
  }

  // per-tile staging split into two 3-load halves (phase A / phase B)
#define STAGE_H0(T, S)                                                         \
  { const int ko = (T) << 5; unsigned short* lb = lds + (S) * SLOT + wave * 512;\
    STG(srcA[0] + ko, lb);                                                     \
    STG(srcA[1] + ko, lb + 2048);                                              \
    STG(srcB[0] + ko, lb + 4096); }
#define STAGE_H1(T, S)                                                         \
  { const int ko = (T) << 5; unsigned short* lb = lds + (S) * SLOT + wave * 512;\
    STG(srcB[1] + ko, lb + 6144);                                              \
    STG(srcB[2] + ko, lb + 8192);                                              \
    STG(srcB[3] + ko, lb + 10240); }

  // -- read-side offsets (shorts). A frag f: row r=f*16+l16, line L=r&63,
  //    j = ((f>>2)<<2)|quad, phys = j^(l16&7). B frag g: row rb=wn+g*16+l16,
  //    line L=rb&127, j = ((wave>>1)<<2)|quad.
  const int x8 = l16 & 7;
  const int ab0 = l16 * 64 + ((quad ^ x8)) * 8;            // A frags 0..3
  const int ab1 = l16 * 64 + (((4 | quad) ^ x8)) * 8;      // A frags 4..7
  const int bb  = 4096 + (wn & 64) * 64 + l16 * 64 +
                  ((((wave >> 1) << 2) | quad) ^ x8) * 8;  // B frags (+g*1024)

  // -- prologue: stage tiles 0,1; gate tile 0 (tile 1's 6 stay in flight) --
  STAGE_H0(0, 0) STAGE_H1(0, 0)
  STAGE_H0(1, 1) STAGE_H1(1, 1)
  asm volatile("s_waitcnt vmcnt(6)" ::: "memory");
  __builtin_amdgcn_s_barrier();

  int st = 0, s2 = 2;
  for (int t = 0; t < NT; ++t) {
    const unsigned short* ls = lds + st * SLOT;

    // ---- phase A: A frags 0..3 + all B frags; stage half 0 of tile t+2 ----
    bf16x8 af0[4], bfv[4];
#pragma unroll
    for (int f = 0; f < 4; f++) af0[f] = *(const bf16x8*)(ls + f * 1024 + ab0);
#pragma unroll
    for (int g = 0; g < 4; g++) bfv[g] = *(const bf16x8*)(ls + g * 1024 + bb);
    if (t + 2 < NT) STAGE_H0(t + 2, s2)
    __builtin_amdgcn_s_barrier();
    __builtin_amdgcn_s_setprio(1);
#pragma unroll
    for (int f = 0; f < 4; f++)
#pragma unroll
      for (int g = 0; g < 4; g++)
        acc[f][g] = __builtin_amdgcn_mfma_f32_16x16x32_bf16(af0[f], bfv[g], acc[f][g], 0, 0, 0);
    __builtin_amdgcn_s_setprio(0);
    __builtin_amdgcn_s_barrier();

    // ---- phase B: A frags 4..7 (B reused); stage half 1; gate once/K-step --
    bf16x8 af1[4];
#pragma unroll
    for (int f = 0; f < 4; f++) af1[f] = *(const bf16x8*)(ls + f * 1024 + ab1);
    if (t + 2 < NT) STAGE_H1(t + 2, s2)
    // gate: tile t+1 fully landed; tile t+2's 6 loads stay in flight
    if (t < NT - 2)       asm volatile("s_waitcnt vmcnt(6)" ::: "memory");
    else if (t == NT - 2) asm volatile("s_waitcnt vmcnt(0)" ::: "memory");
    __builtin_amdgcn_s_barrier();
    __builtin_amdgcn_s_setprio(1);
#pragma unroll
    for (int f = 0; f < 4; f++)
#pragma unroll
      for (int g = 0; g < 4; g++)
        acc[f + 4][g] = __builtin_amdgcn_mfma_f32_16x16x32_bf16(af1[f], bfv[g], acc[f + 4][g], 0, 0, 0);
    __builtin_amdgcn_s_setprio(0);
    if (t < NT - 1) __builtin_amdgcn_s_barrier();

    st++; if (st == 3) st = 0;
    s2++; if (s2 == 3) s2 = 0;
  }
#undef STAGE_H0
#undef STAGE_H1

  // ---- epilogue: C write ----
#pragma unroll
  for (int f = 0; f < 8; f++)
#pragma unroll
    for (int g = 0; g < 4; g++) {
      const size_t row = (size_t)(m0 + f * 16 + quad * 4);
      const int col = n0 + wn + g * 16 + l16;
      if (BF16OUT) {
        unsigned short* cp = (unsigned short*)Cv + row * DM + col;
#pragma unroll
        for (int r = 0; r < 4; r++) cp[(size_t)r * DM] = f2bf(acc[f][g][r]);
      } else {
        float* cp = (float*)Cv + row * DM + col;
#pragma unroll
        for (int r = 0; r < 4; r++) cp[(size_t)r * DM] = acc[f][g][r];
      }
    }
}

// ---------------- batched QKV GEMM: P[z] = A[z] * W[z]^T, bf16 out ----------
__global__ __launch_bounds__(256, 2) void gemm_qkv(const unsigned short* __restrict__ xb,
                                                   const unsigned short* __restrict__ cb,
                                                   const unsigned short* __restrict__ Wq,
                                                   const unsigned short* __restrict__ Wk,
                                                   const unsigned short* __restrict__ Wv,
                                                   unsigned short* __restrict__ Pq,
                                                   unsigned short* __restrict__ Pk,
                                                   unsigned short* __restrict__ Pv) {
  __shared__ __align__(16) unsigned short lds[3 * 12288];  // 72 KiB
  const int z = blockIdx.z;
  const unsigned short* A  = (z == 0) ? xb : cb;
  const unsigned short* Bw = (z == 0) ? Wq : (z == 1) ? Wk : Wv;
  unsigned short* C        = (z == 0) ? Pq : (z == 1) ? Pk : Pv;
  gemm_core<1, 64>(A, Bw, C, lds);
}

// ---------------- out-proj split-K=2: partial C = A[:,z*1024:] * Wo^T -------
__global__ __launch_bounds__(256, 2) void gemm_bt(const unsigned short* __restrict__ A,
                                                  const unsigned short* __restrict__ Bw,
                                                  float* __restrict__ C1,
                                                  float* __restrict__ C2) {
  __shared__ __align__(16) unsigned short lds[3 * 12288];  // 72 KiB
  const int z = blockIdx.z;
  gemm_core<0, 32>(A + (z << 10), Bw + (z << 10),
                   z ? (void*)C2 : (void*)C1, lds);
}

// ---------------- out = C1 + C2 (fp32, vec4) ----------------
__global__ __launch_bounds__(256) void addout(const float4* __restrict__ a,
                                              const float4* __restrict__ b,
                                              float4* __restrict__ o, int n4) {
  int i = blockIdx.x * 256 + threadIdx.x;
  if (i >= n4) return;
  float4 x = a[i], y = b[i];
  o[i] = make_float4(x.x + y.x, x.y + y.y, x.z + y.z, x.w + y.w);
}

// ---------------- fused RMSNorm + RoPE body (one warp per (b,s,h) row) ------
__device__ __forceinline__ void normrope_body(int bid,
                                              const unsigned short* __restrict__ X,
                                              const float* __restrict__ Cs,
                                              const float* __restrict__ Sn,
                                              const float* __restrict__ W,
                                              unsigned short* __restrict__ Out,
                                              float scale) {
  int gw = (bid * 256 + threadIdx.x) >> 6;  // (b*S+s)*H + h
  int lane = threadIdx.x & 63;
  int h = gw & 15, bs = gw >> 4;          // bs = b*S + s
  int s = bs & (S_ - 1), b = bs >> 11;
  const unsigned short* xr = X + (size_t)gw * HD;
  float x0 = bf2f(xr[lane]), x1 = bf2f(xr[lane + 64]);
  float ss = x0 * x0 + x1 * x1;
#pragma unroll
  for (int off = 32; off > 0; off >>= 1) ss += __shfl_xor(ss, off);
  float rr = rsqrtf(ss * (1.0f / 128.0f) + 1e-6f);
  float n0 = x0 * rr * W[lane], n1 = x1 * rr * W[lane + 64];
  const float* cp = Cs + (size_t)bs * HD;
  const float* sp = Sn + (size_t)bs * HD;
  float o0 = (n0 * cp[lane] - n1 * sp[lane]) * scale;
  float o1 = (n1 * cp[lane + 64] + n0 * sp[lane + 64]) * scale;
  unsigned short* orow = Out + (((size_t)(b * H_ + h)) * S_ + s) * HD;
  orow[lane] = f2bf(o0);
  orow[lane + 64] = f2bf(o1);
}

// ---------------- V transpose body: (B,S,H,hd) -> (B*H, hd, Sk) -------------
__device__ __forceinline__ void vtrans_body(int bid,
                                            const unsigned short* __restrict__ Vf,
                                            unsigned short* __restrict__ Vt,
                                            unsigned short* tile) {
  const int tid = threadIdx.x;
  const int sc = bid & 31;
  const int bh = bid >> 5;
  const int b = bh >> 4, h = bh & 15;
  const int s0 = sc * 64;
#pragma unroll
  for (int it = 0; it < 4; ++it) {
    int ci = it * 256 + tid;                  // 1024 chunks: 64 s x 16 dc
    int s = ci >> 4, dc = ci & 15;
    bf16x8 v = *(const bf16x8*)(Vf + ((size_t)(b * S_ + s0 + s)) * DM + h * HD + dc * 8);
    unsigned short* tp = tile + (dc * 8) * 72 + s;
#pragma unroll
    for (int e = 0; e < 8; e++) tp[e * 72] = (unsigned short)v[e];
  }
  __syncthreads();
#pragma unroll
  for (int it = 0; it < 4; ++it) {
    int cj = it * 256 + tid;                  // 1024 16B chunks: 128 d x 8 sc
    int d = cj >> 3, scx = cj & 7;
    bf16x8 vv = *(const bf16x8*)(tile + d * 72 + scx * 8);
    *(bf16x8*)(Vt + ((size_t)bh * HD + d) * S_ + s0 + scx * 8) = vv;
  }
}

// ---------------- prep: normrope(Q) + normrope(K) + vtrans in one launch ----
__global__ __launch_bounds__(256) void prep(const unsigned short* __restrict__ Pq,
                                            const unsigned short* __restrict__ Pk,
                                            const unsigned short* __restrict__ Pv,
                                            const float* __restrict__ cq,
                                            const float* __restrict__ sq,
                                            const float* __restrict__ ck,
                                            const float* __restrict__ sk,
                                            const float* __restrict__ qw,
                                            const float* __restrict__ kw,
                                            unsigned short* __restrict__ qn,
                                            unsigned short* __restrict__ kn,
                                            unsigned short* __restrict__ vt,
                                            float scale) {
  __shared__ unsigned short tile[128 * 72];
  constexpr int NR = M_ * H_ / 4;   // 16384 blocks per normrope
  int bx = blockIdx.x;
  if (bx < NR)            normrope_body(bx, Pq, cq, sq, qw, qn, scale);
  else if (bx < 2 * NR)   normrope_body(bx - NR, Pk, ck, sk, kw, kn, 1.0f);
  else                    vtrans_body(bx - 2 * NR, Pv, vt, tile);
}

// ---------------- flash attention v4 (R6, unchanged) ----------------
// 256 threads (4 waves), 128 q-rows/block (32/wave), 64-key chunks.
// K/V double-buffered; stage t+1 during compute of t; counted vmcnt(8);
// raw s_barriers; drain only at final iter. Grid 512 = 2 blocks/CU.
__global__ __launch_bounds__(256, 2) void flash(const unsigned short* __restrict__ Q,
                                                const unsigned short* __restrict__ Kt,
                                                const unsigned short* __restrict__ Vt,
                                                unsigned short* __restrict__ Y) {
  __shared__ unsigned short lK[2 * 64 * HD];  // [buf][key][dim], chunk-swizzled
  __shared__ unsigned short lV[2 * HD * 64];  // [buf][dim][key], chunk-swizzled
  __shared__ unsigned short lP[4 * 1024];     // per-wave P scratch (reused per half)
  const int tid = threadIdx.x, wave = tid >> 6, lane = tid & 63;
  const int quad = lane >> 4, l16 = lane & 15;
  const int qb = blockIdx.x & 15;   // Sq/128
  const int bh = blockIdx.x >> 4;
  const int b = bh >> 4, h = bh & 15;
  const int q0 = qb * 128 + wave * 32;

  bf16x8 aq[2][4];
#pragma unroll
  for (int u = 0; u < 2; u++) {
    const unsigned short* qrow = Q + ((size_t)bh * S_ + q0 + u * 16 + l16) * HD;
#pragma unroll
    for (int t = 0; t < 4; t++) aq[u][t] = *(const bf16x8*)(qrow + t * 32 + quad * 8);
  }
  f32x4 o[2][8];
#pragma unroll
  for (int u = 0; u < 2; u++)
#pragma unroll
    for (int t = 0; t < 8; t++) o[u][t] = (f32x4){0.f, 0.f, 0.f, 0.f};
  float lsum[2][4] = {{0.f, 0.f, 0.f, 0.f}, {0.f, 0.f, 0.f, 0.f}};

  const unsigned short* kbase = Kt + (size_t)bh * S_ * HD;
  const unsigned short* vbase = Vt + (size_t)bh * HD * S_;
  unsigned short* lPw = lP + wave * 1024;
  const int mrow = quad * 4;
  const int xsl = (l16 >> 1) & 3;    // P-read swizzle (4 chunks per 32-key row)
  const int xsl7 = (l16 >> 1) & 7;   // V-read swizzle (8 chunks per 64-key row)

#define STAGEKV(K0, BUF)                                                       \
  {                                                                            \
    const unsigned short* kb_ = kbase + (size_t)(K0) * HD;                     \
    const unsigned short* vb_ = vbase + (K0);                                  \
    _Pragma("unroll")                                                          \
    for (int call = 0; call < 4; ++call) {                                     \
      int c = call * 256 + tid;               /* chunk id [0,1024) */          \
      int key = c >> 4, sk = c & 15;          /* K: 64 keys x 16 dim-chunks */ \
      int dck = sk ^ (key & 15);                                               \
      STG(kb_ + (size_t)key * HD + dck * 8,                                    \
          lK + (BUF) * 8192 + (call * 256 + wave * 64) * 8);                   \
      int dv = c >> 3, sv = c & 7;            /* V: 128 dims x 8 key-chunks */ \
      int kc = sv ^ ((dv >> 1) & 7);                                           \
      STG(vb_ + (size_t)dv * S_ + kc * 8,                                      \
          lV + (BUF) * 8192 + (call * 256 + wave * 64) * 8);                   \
    }                                                                          \
  }

  STAGEKV(0, 0)

  for (int it = 0; it < S_ / 64; ++it) {
    if (it + 1 < S_ / 64) {
      STAGEKV((it + 1) * 64, (it + 1) & 1)
      asm volatile("s_waitcnt vmcnt(8)" ::: "memory");
    } else {
      asm volatile("s_waitcnt vmcnt(0)" ::: "memory");
    }
    __builtin_amdgcn_s_barrier();   // publish all waves' stages of tile `it`

    const unsigned short* lKc = lK + (it & 1) * 8192;
    const unsigned short* lVc = lV + (it & 1) * 8192;

#pragma unroll
    for (int h2 = 0; h2 < 2; ++h2) {          // two 32-key halves
      f32x4 s0[2] = {(f32x4){0.f, 0.f, 0.f, 0.f}, (f32x4){0.f, 0.f, 0.f, 0.f}};
      f32x4 s1[2] = {(f32x4){0.f, 0.f, 0.f, 0.f}, (f32x4){0.f, 0.f, 0.f, 0.f}};
      {
        const unsigned short* krow0 = lKc + (h2 * 32 + l16) * HD;
        const unsigned short* krow1 = krow0 + 16 * HD;
        __builtin_amdgcn_s_setprio(1);
#pragma unroll
        for (int t = 0; t < 4; t++) {
          int dcq = t * 4 + quad;
          bf16x8 kf0 = *(const bf16x8*)(krow0 + (dcq ^ l16) * 8);
          bf16x8 kf1 = *(const bf16x8*)(krow1 + (dcq ^ l16) * 8);
#pragma unroll
          for (int u = 0; u < 2; u++) {
            s0[u] = __builtin_amdgcn_mfma_f32_16x16x32_bf16(aq[u][t], kf0, s0[u], 0, 0, 0);
            s1[u] = __builtin_amdgcn_mfma_f32_16x16x32_bf16(aq[u][t], kf1, s1[u], 0, 0, 0);
          }
        }
        __builtin_amdgcn_s_setprio(0);
      }
#pragma unroll
      for (int u = 0; u < 2; u++) {
        unsigned short* lPu = lPw + u * 512;
#pragma unroll
        for (int r = 0; r < 4; r++) {
          int m = mrow + r;
          int sx = (m >> 1) & 3;
          float p0 = __expf(s0[u][r]);
          float p1 = __expf(s1[u][r]);
          lsum[u][r] += p0 + p1;
          int kc0 = l16 >> 3;
          lPu[m * 32 + ((kc0 ^ sx)) * 8 + (l16 & 7)] = f2bf(p0);
          lPu[m * 32 + (((kc0 + 2) ^ sx)) * 8 + (l16 & 7)] = f2bf(p1);
        }
      }
      bf16x8 pf[2];
#pragma unroll
      for (int u = 0; u < 2; u++)
        pf[u] = *(const bf16x8*)(lPw + u * 512 + l16 * 32 + (quad ^ xsl) * 8);
      __builtin_amdgcn_s_setprio(1);
#pragma unroll
      for (int t = 0; t < 8; t++) {
        bf16x8 vf = *(const bf16x8*)(lVc + (t * 16 + l16) * 64 + ((h2 * 4 + quad) ^ xsl7) * 8);
#pragma unroll
        for (int u = 0; u < 2; u++)
          o[u][t] = __builtin_amdgcn_mfma_f32_16x16x32_bf16(pf[u], vf, o[u][t], 0, 0, 0);
      }
      __builtin_amdgcn_s_setprio(0);
    }

    __builtin_amdgcn_s_barrier();   // reads of buf (it&1) done before overwrite
  }
#undef STAGEKV

#pragma unroll
  for (int off = 1; off < 16; off <<= 1) {
#pragma unroll
    for (int u = 0; u < 2; u++)
#pragma unroll
      for (int r = 0; r < 4; r++) lsum[u][r] += __shfl_xor(lsum[u][r], off);
  }
  float inv[2][4];
#pragma unroll
  for (int u = 0; u < 2; u++)
#pragma unroll
    for (int r = 0; r < 4; r++) inv[u][r] = 1.0f / lsum[u][r];
#pragma unroll
  for (int u = 0; u < 2; u++)
#pragma unroll
    for (int t = 0; t < 8; t++)
#pragma unroll
      for (int r = 0; r < 4; r++) {
        size_t idx = ((size_t)b * S_ + q0 + u * 16 + mrow + r) * DM + h * HD + t * 16 + l16;
        Y[idx] = f2bf(o[u][t][r] * inv[u][r]);
      }
}

// ============================================================================
extern "C" void kernel_launch(void* const* d_in, const int* in_sizes, int n_in,
                              void* d_out, int out_size, void* d_ws, size_t ws_size,
                              hipStream_t stream) {
  const float* x    = (const float*)d_in[0];
  const float* ctx  = (const float*)d_in[1];
  const float* cosq = (const float*)d_in[2];
  const float* sinq = (const float*)d_in[3];
  const float* cosk = (const float*)d_in[4];
  const float* sink = (const float*)d_in[5];
  const float* Wq   = (const float*)d_in[6];
  const float* Wk   = (const float*)d_in[7];
  const float* Wv   = (const float*)d_in[8];
  const float* Wo   = (const float*)d_in[9];
  const float* qw   = (const float*)d_in[10];
  const float* kw   = (const float*)d_in[11];

  // ---- workspace layout with lifetime overlap (~118 MB) ----
  char* ws = (char*)d_ws;
  const size_t ACT2 = (size_t)M_ * DM * 2;   // 16.8 MB bf16 activation
  const size_t W2   = (size_t)DM * DM * 2;   // 8.4 MB bf16 weight
  unsigned short* xb  = (unsigned short*)(ws);                    // -> qn -> C2
  unsigned short* cb  = (unsigned short*)(ws + ACT2);             // -> vt
  unsigned short* Wqb = (unsigned short*)(ws + 2 * ACT2);         // \ kn
  unsigned short* Wkb = (unsigned short*)(ws + 2 * ACT2 + W2);    // /
  unsigned short* Wvb = (unsigned short*)(ws + 2 * ACT2 + 2 * W2);
  unsigned short* Wob = (unsigned short*)(ws + 2 * ACT2 + 3 * W2);
  unsigned short* Pq  = (unsigned short*)(ws + 2 * ACT2 + 4 * W2);  // -> yb
  unsigned short* Pk  = (unsigned short*)(ws + 3 * ACT2 + 4 * W2);  // -> C1
  unsigned short* Pv  = (unsigned short*)(ws + 4 * ACT2 + 4 * W2);
  unsigned short* qn = xb;          // after gemm_qkv consumed xb
  unsigned short* kn = Wqb;         // spans Wqb+Wkb, dead after gemm_qkv
  unsigned short* vt = cb;          // after gemm_qkv consumed cb
  unsigned short* yb = Pq;          // after prep consumed Pq
  float* C1 = (float*)Pk;           // spans Pk+Pv (33.6 MB), dead after flash
  float* C2 = (float*)xb;           // spans xb+cb (33.6 MB), dead after flash

  const float scale = 0.0883883476483184f;  // 1/sqrt(128)

  // one cast launch for all 6 tensors
  castall<<<(2 * M_ * DM + 4 * DM * DM) / 1024, 256, 0, stream>>>(
      x, ctx, Wq, Wk, Wv, Wo, xb, cb, Wqb, Wkb, Wvb, Wob);

  dim3 gq(M_ / 128, DM / 256, 3);   // 32 x 8 x 3 = 768 blocks (2 per CU)
  gemm_qkv<<<gq, 256, 0, stream>>>(xb, cb, Wqb, Wkb, Wvb, Pq, Pk, Pv);

  // normrope(Q) + normrope(K) + vtrans, one launch
  prep<<<2 * (M_ * H_ / 4) + B_ * H_ * (S_ / 64), 256, 0, stream>>>(
      Pq, Pk, Pv, cosq, sinq, cosk, sink, qw, kw, qn, kn, vt, scale);

  flash<<<B_ * H_ * (S_ / 128), 256, 0, stream>>>(qn, kn, vt, yb);

  dim3 gg(M_ / 128, DM / 256, 2);   // 32 x 8 x 2 = 512 blocks = exact 2/CU fill
  gemm_bt<<<gg, 256, 0, stream>>>(yb, Wob, C1, C2);

  addout<<<M_ * DM / 1024, 256, 0, stream>>>((const float4*)C1, (const float4*)C2,
                                             (float4*)d_out, M_ * DM / 4);

  (void)in_sizes; (void)n_in; (void)out_size; (void)ws_size;
}